// Round 3
// baseline (221.877 us; speedup 1.0000x reference)
//
#include <hip/hip_runtime.h>
#include <cstdint>

// BinarizedLeNet5 / CIFAR10, B=2048.  Round 3: full per-sample fusion.
//  k0_pack : all weight/bn preprocessing (unchanged from round 2, passing).
//  kmega   : one block per sample; conv1+pool+bn1 -> conv2+pool+bn2 -> fc1+bn3
//            -> fc2+bn4+clip -> fc3+log_softmax, intermediates in LDS only.
// Every phase's arithmetic is verbatim from the round-2 kernels (absmax 0.0);
// only data movement changed (LDS instead of global round-trips).

#define BSZ 2048

__device__ __forceinline__ float sgnf(float w) {
    return (w > 0.f) ? 1.f : ((w < 0.f) ? -1.f : 0.f);
}

// ---------------- k0: all packing ----------------
__global__ __launch_bounds__(256) void k0_pack(
    const float* __restrict__ c1w, const float* __restrict__ c2w,
    const float* __restrict__ f1w, const float* __restrict__ f2w,
    const float* __restrict__ c1b, const float* __restrict__ c2b,
    const float* __restrict__ f1b, const float* __restrict__ f2b,
    const float* __restrict__ b1g, const float* __restrict__ b1b,
    const float* __restrict__ b1m, const float* __restrict__ b1v,
    const float* __restrict__ b2g, const float* __restrict__ b2b,
    const float* __restrict__ b2m, const float* __restrict__ b2v,
    const float* __restrict__ b3g, const float* __restrict__ b3b,
    const float* __restrict__ b3m, const float* __restrict__ b3v,
    const float* __restrict__ b4g, const float* __restrict__ b4b,
    const float* __restrict__ b4m, const float* __restrict__ b4v,
    float* __restrict__ sw1, uint32_t* __restrict__ wp2,
    uint32_t* __restrict__ wpf1, uint32_t* __restrict__ wpf2,
    float* __restrict__ bnp1, float* __restrict__ bnp2,
    float* __restrict__ bnp3, float* __restrict__ bnp4) {
    int bid = blockIdx.x, t = threadIdx.x;
    if (bid < 1024) {
        // fc1 pack: wave W covers 512 consecutive elements of row o.
        int W = bid * 4 + (t >> 6), l = t & 63;
        int o = W >> 3, chunk = W & 7;
        const float* row = f1w + (size_t)o * 4096 + chunk * 512;
        int kwb = chunk * 16;
#pragma unroll
        for (int j = 0; j < 8; j++) {
            float vj = row[j * 64 + l];
            unsigned long long mk = __ballot(vj > 0.f);
            if (l == 0) {
                wpf1[(size_t)(kwb + 2 * j) * 512 + o] = (uint32_t)mk;
                wpf1[(size_t)(kwb + 2 * j + 1) * 512 + o] = (uint32_t)(mk >> 32);
            }
        }
    } else if (bid == 1024) {
        for (int i = t; i < 1024; i += 256) {
            int o = i >> 4, k = i & 15;
            uint32_t word = 0;
            if (k < 9)
                for (int c = 0; c < 32; c++)
                    if (c2w[(o * 32 + c) * 9 + k] > 0.f) word |= (1u << c);
            wp2[i] = word;
        }
        if (t < 64) {
            float inv = __fdiv_rn(b2g[t], __fsqrt_rn(b2v[t] + 1e-5f));
            float add = __fsub_rn(b2b[t], __fmul_rn(b2m[t], inv));
            bnp2[t * 4] = inv; bnp2[t * 4 + 1] = add;
            bnp2[t * 4 + 2] = c2b[t]; bnp2[t * 4 + 3] = 0.f;
        }
    } else if (bid == 1025) {
        for (int i = t; i < 1024; i += 256) {
            int o = i >> 5, r = i & 31;
            sw1[i] = (r < 27) ? sgnf(c1w[o * 27 + r]) : 0.f;
        }
        if (t < 32) {
            float inv = __fdiv_rn(b1g[t], __fsqrt_rn(b1v[t] + 1e-5f));
            float add = __fsub_rn(b1b[t], __fmul_rn(b1m[t], inv));
            bnp1[t * 4] = inv; bnp1[t * 4 + 1] = add;
            bnp1[t * 4 + 2] = c1b[t]; bnp1[t * 4 + 3] = 0.f;
        }
    } else if (bid < 1042) {
        int i = (bid - 1026) * 256 + t;       // 4096 = [16 k][256 o]
        int k = i >> 8, o = i & 255;
        const float* r = f2w + (size_t)o * 512 + k * 32;
        uint32_t word = 0;
#pragma unroll
        for (int j = 0; j < 32; j++)
            if (r[j] > 0.f) word |= (1u << j);
        wpf2[k * 256 + o] = word;
    } else {
        for (int i = t; i < 512; i += 256) {
            float inv = __fdiv_rn(b3g[i], __fsqrt_rn(b3v[i] + 1e-5f));
            float add = __fsub_rn(b3b[i], __fmul_rn(b3m[i], inv));
            bnp3[i * 4] = inv; bnp3[i * 4 + 1] = add;
            bnp3[i * 4 + 2] = f1b[i]; bnp3[i * 4 + 3] = 0.f;
        }
        if (t < 256) {
            float inv = __fdiv_rn(b4g[t], __fsqrt_rn(b4v[t] + 1e-5f));
            float add = __fsub_rn(b4b[t], __fmul_rn(b4m[t], inv));
            bnp4[t * 4] = inv; bnp4[t * 4 + 1] = add;
            bnp4[t * 4 + 2] = f2b[t]; bnp4[t * 4 + 3] = 0.f;
        }
    }
}

// ---------------- kmega: whole network, one block per sample ----------------
__global__ __launch_bounds__(256) void kmega(
    const float* __restrict__ x, const float* __restrict__ sw,
    const float* __restrict__ bnp1, const uint32_t* __restrict__ wp2,
    const float* __restrict__ bnp2, const uint32_t* __restrict__ wpf1,
    const float* __restrict__ bnp3, const uint32_t* __restrict__ wpf2,
    const float* __restrict__ bnp4, const float* __restrict__ f3w,
    const float* __restrict__ f3b, float* __restrict__ out) {
    const int P = 19;
    __shared__ uint32_t tile[18 * 19];       // conv2 input, zero-padded
    __shared__ uint32_t fc1in[128];          // fc1 input bits
    __shared__ uint32_t fc2in[16];           // fc2 input bits
    __shared__ float4 hbuf4[64];             // fc3 input (clipped bn4)
    int b = blockIdx.x, t = threadIdx.x;
    int wv = t >> 6, l = t & 63;

    // zero-init pad cells (whole tile; interior overwritten after barrier)
    for (int i = t; i < 18 * 19; i += 256) tile[i] = 0;

    // ---- phase 1: conv1 + pool + bn1 + sign-pack -> tile ----
    {
        int py = t >> 4, px = t & 15;
        int y0 = 2 * py - 1, x0 = 2 * px - 1;
        float in[48];
#pragma unroll
        for (int c = 0; c < 3; c++) {
            const float* xc = x + ((size_t)b * 3 + c) * 1024;
#pragma unroll
            for (int i = 0; i < 4; i++) {
                int yy = y0 + i;
                bool ry = (unsigned)yy < 32u;
#pragma unroll
                for (int j = 0; j < 4; j++) {
                    int xx = x0 + j;
                    in[c * 16 + i * 4 + j] =
                        (ry && (unsigned)xx < 32u) ? xc[yy * 32 + xx] : 0.f;
                }
            }
        }
        uint32_t word = 0;
#pragma unroll 2
        for (int o = 0; o < 32; o++) {
            const float* wo = sw + o * 32;           // uniform -> s_load
            float a00 = 0.f, a01 = 0.f, a10 = 0.f, a11 = 0.f;
#pragma unroll
            for (int c = 0; c < 3; c++)
#pragma unroll
                for (int ky = 0; ky < 3; ky++)
#pragma unroll
                    for (int kx = 0; kx < 3; kx++) {
                        float wvv = wo[c * 9 + ky * 3 + kx];
                        a00 = fmaf(in[c * 16 + ky * 4 + kx], wvv, a00);
                        a01 = fmaf(in[c * 16 + ky * 4 + kx + 1], wvv, a01);
                        a10 = fmaf(in[c * 16 + (ky + 1) * 4 + kx], wvv, a10);
                        a11 = fmaf(in[c * 16 + (ky + 1) * 4 + kx + 1], wvv, a11);
                    }
            float4 p = ((const float4*)bnp1)[o];     // uniform -> s_load
            float mx = fmaxf(fmaxf(a00, a01), fmaxf(a10, a11));
            float h = __fadd_rn(mx, p.z);
            float val = __fadd_rn(__fmul_rn(h, p.x), p.y);
            word |= (val > 0.f) ? (1u << o) : 0u;
        }
        __syncthreads();                             // pad-init done everywhere
        tile[(py + 1) * P + px + 1] = word;
    }
    __syncthreads();

    // ---- phase 2: conv2 xnor-popc + pool + bn2 + sign-pack -> fc1in ----
    {
        int py = l >> 3, px = l & 7;
        uint32_t val[16];
#pragma unroll
        for (int i = 0; i < 4; i++)
#pragma unroll
            for (int j = 0; j < 4; j++)
                val[i * 4 + j] = tile[(2 * py + i) * P + 2 * px + j];
        bool top = (py == 0), bot = (py == 7), lef = (px == 0), rig = (px == 7);
        bool ctl = top && lef, ctr = top && rig, cbl = bot && lef, cbr = bot && rig;
#pragma unroll 2
        for (int oi = 0; oi < 16; oi++) {
            int o = wv * 16 + oi;
            const uint32_t* wo = wp2 + o * 16;       // uniform -> s_load
            uint32_t w0 = wo[0], w1 = wo[1], w2 = wo[2], w3 = wo[3], w4 = wo[4],
                     w5 = wo[5], w6 = wo[6], w7 = wo[7], w8 = wo[8];
            int t0 = 32 - 2 * __popc(w0), t1 = 32 - 2 * __popc(w1),
                t2 = 32 - 2 * __popc(w2), t3 = 32 - 2 * __popc(w3),
                t5 = 32 - 2 * __popc(w5), t6 = 32 - 2 * __popc(w6),
                t7 = 32 - 2 * __popc(w7), t8 = 32 - 2 * __popc(w8);
            int R0 = t0 + t1 + t2, R2 = t6 + t7 + t8;
            int C0 = t0 + t3 + t6, C2 = t2 + t5 + t8;
            int P00 = __popc(val[0] ^ w0) + __popc(val[1] ^ w1) + __popc(val[2] ^ w2) +
                      __popc(val[4] ^ w3) + __popc(val[5] ^ w4) + __popc(val[6] ^ w5) +
                      __popc(val[8] ^ w6) + __popc(val[9] ^ w7) + __popc(val[10] ^ w8);
            int P01 = __popc(val[1] ^ w0) + __popc(val[2] ^ w1) + __popc(val[3] ^ w2) +
                      __popc(val[5] ^ w3) + __popc(val[6] ^ w4) + __popc(val[7] ^ w5) +
                      __popc(val[9] ^ w6) + __popc(val[10] ^ w7) + __popc(val[11] ^ w8);
            int P10 = __popc(val[4] ^ w0) + __popc(val[5] ^ w1) + __popc(val[6] ^ w2) +
                      __popc(val[8] ^ w3) + __popc(val[9] ^ w4) + __popc(val[10] ^ w5) +
                      __popc(val[12] ^ w6) + __popc(val[13] ^ w7) + __popc(val[14] ^ w8);
            int P11 = __popc(val[5] ^ w0) + __popc(val[6] ^ w1) + __popc(val[7] ^ w2) +
                      __popc(val[9] ^ w3) + __popc(val[10] ^ w4) + __popc(val[11] ^ w5) +
                      __popc(val[13] ^ w6) + __popc(val[14] ^ w7) + __popc(val[15] ^ w8);
            int s00 = 288 - 2 * P00 - ((top ? R0 : 0) + (lef ? C0 : 0) - (ctl ? t0 : 0));
            int s01 = 288 - 2 * P01 - ((top ? R0 : 0) + (rig ? C2 : 0) - (ctr ? t2 : 0));
            int s10 = 288 - 2 * P10 - ((bot ? R2 : 0) + (lef ? C0 : 0) - (cbl ? t6 : 0));
            int s11 = 288 - 2 * P11 - ((bot ? R2 : 0) + (rig ? C2 : 0) - (cbr ? t8 : 0));
            int mi = max(max(s00, s01), max(s10, s11));
            float4 p = ((const float4*)bnp2)[o];     // uniform -> s_load
            float h = __fadd_rn((float)mi, p.z);
            float bv = __fadd_rn(__fmul_rn(h, p.x), p.y);
            unsigned long long mk = __ballot(bv > 0.f);
            if (l == 0) {
                fc1in[2 * o] = (uint32_t)mk;
                fc1in[2 * o + 1] = (uint32_t)(mk >> 32);
            }
        }
    }
    __syncthreads();

    // ---- phase 3: fc1 xnor-popc + bn3 + sign-pack -> fc2in ----
#pragma unroll
    for (int p2 = 0; p2 < 2; p2++) {
        int obase = p2 * 256 + wv * 64;
        int o = obase + l;
        float4 p = ((const float4*)bnp3)[o];         // per-lane, coalesced
        int acc = 0;
#pragma unroll 8
        for (int k = 0; k < 128; k++)
            acc += __popc(wpf1[k * 512 + o] ^ fc1in[k]);  // LDS broadcast
        float h = __fadd_rn((float)(4096 - 2 * acc), p.z);
        float bv = __fadd_rn(__fmul_rn(h, p.x), p.y);
        unsigned long long mk = __ballot(bv > 0.f);
        if (l == 0) {
            fc2in[obase >> 5] = (uint32_t)mk;
            fc2in[(obase >> 5) + 1] = (uint32_t)(mk >> 32);
        }
    }
    __syncthreads();

    // ---- phase 4: fc2 xnor-popc + bn4 + clip -> hbuf ----
    {
        int acc = 0;
#pragma unroll
        for (int k = 0; k < 16; k++)
            acc += __popc(wpf2[k * 256 + t] ^ fc2in[k]);
        float4 p = ((const float4*)bnp4)[t];
        float h = __fadd_rn((float)(512 - 2 * acc), p.z);
        float bv = __fadd_rn(__fmul_rn(h, p.x), p.y);
        bv = fminf(1.f, fmaxf(-1.f, bv));
        ((float*)hbuf4)[t] = bv;
    }
    __syncthreads();

    // ---- phase 5: fc3 + log_softmax (wave 0 only) ----
    if (t < 64) {
        float4 hv = hbuf4[t];
        float logits[10];
#pragma unroll
        for (int j = 0; j < 10; j++) {
            const float4* wp4 = (const float4*)(f3w + j * 256);
            float4 w4 = wp4[t];
            float pp = hv.x * w4.x + hv.y * w4.y + hv.z * w4.z + hv.w * w4.w;
#pragma unroll
            for (int off = 32; off > 0; off >>= 1) pp += __shfl_xor(pp, off, 64);
            logits[j] = pp + f3b[j];
        }
        float mx = logits[0];
#pragma unroll
        for (int j = 1; j < 10; j++) mx = fmaxf(mx, logits[j]);
        float sum = 0.f;
#pragma unroll
        for (int j = 0; j < 10; j++) sum += expf(logits[j] - mx);
        float ls = mx + logf(sum);
        if (t < 10) out[(size_t)b * 10 + t] = logits[t] - ls;
    }
}

extern "C" void kernel_launch(void* const* d_in, const int* in_sizes, int n_in,
                              void* d_out, int out_size, void* d_ws, size_t ws_size,
                              hipStream_t stream) {
    (void)in_sizes; (void)n_in; (void)out_size; (void)ws_size;
    const float* x   = (const float*)d_in[0];
    const float* c1w = (const float*)d_in[1];
    const float* c1b = (const float*)d_in[2];
    const float* b1g = (const float*)d_in[3];
    const float* b1b = (const float*)d_in[4];
    const float* b1m = (const float*)d_in[5];
    const float* b1v = (const float*)d_in[6];
    const float* c2w = (const float*)d_in[7];
    const float* c2b = (const float*)d_in[8];
    const float* b2g = (const float*)d_in[9];
    const float* b2b = (const float*)d_in[10];
    const float* b2m = (const float*)d_in[11];
    const float* b2v = (const float*)d_in[12];
    const float* f1w = (const float*)d_in[13];
    const float* f1b = (const float*)d_in[14];
    const float* b3g = (const float*)d_in[15];
    const float* b3b = (const float*)d_in[16];
    const float* b3m = (const float*)d_in[17];
    const float* b3v = (const float*)d_in[18];
    const float* f2w = (const float*)d_in[19];
    const float* f2b = (const float*)d_in[20];
    const float* b4g = (const float*)d_in[21];
    const float* b4b = (const float*)d_in[22];
    const float* b4m = (const float*)d_in[23];
    const float* b4v = (const float*)d_in[24];
    const float* f3w = (const float*)d_in[25];
    const float* f3b = (const float*)d_in[26];
    float* out = (float*)d_out;

    uint8_t* ws = (uint8_t*)d_ws;
    float*    sw1  = (float*)   (ws + 0);         // [32,32] signed conv1 w
    uint32_t* wp2  = (uint32_t*)(ws + 4096);      // [64,16] conv2 bits
    uint32_t* wpf1 = (uint32_t*)(ws + 8192);      // [128,512] fc1 bits^T
    uint32_t* wpf2 = (uint32_t*)(ws + 270336);    // [16,256]  fc2 bits^T
    float*    bnp1 = (float*)   (ws + 286720);    // [32]  {inv,add,bias,0}
    float*    bnp2 = (float*)   (ws + 287232);    // [64]
    float*    bnp3 = (float*)   (ws + 288256);    // [512]
    float*    bnp4 = (float*)   (ws + 296448);    // [256]

    k0_pack<<<1043, 256, 0, stream>>>(c1w, c2w, f1w, f2w, c1b, c2b, f1b, f2b,
                                      b1g, b1b, b1m, b1v, b2g, b2b, b2m, b2v,
                                      b3g, b3b, b3m, b3v, b4g, b4b, b4m, b4v,
                                      sw1, wp2, wpf1, wpf2, bnp1, bnp2, bnp3, bnp4);
    kmega<<<BSZ, 256, 0, stream>>>(x, sw1, bnp1, wp2, bnp2, wpf1, bnp3, wpf2,
                                   bnp4, f3w, f3b, out);
}